// Round 11
// baseline (387.984 us; speedup 1.0000x reference)
//
#include <hip/hip_runtime.h>
#include <hip/hip_bf16.h>

#define B_ 2
#define S_ 2048
#define D_ 1024
#define H_ 16
#define HD_ 64

typedef __attribute__((ext_vector_type(8))) short short8;
typedef __attribute__((ext_vector_type(4))) short short4v;
typedef __attribute__((ext_vector_type(4))) float float4v;

typedef const __attribute__((address_space(1))) void* gas_ptr;
typedef __attribute__((address_space(3))) void* las_ptr;

static __device__ inline void gl_lds16(const void* g, void* l) {
  __builtin_amdgcn_global_load_lds((gas_ptr)g, (las_ptr)l, 16, 0, 0);
}

static __device__ inline float b2f(__hip_bfloat16 h) { return __bfloat162float(h); }

static __device__ inline short f2bs(float x) {
  __hip_bfloat16 h = __float2bfloat16(x);
  union { __hip_bfloat16 h; short s; } u; u.h = h; return u.s;
}
static __device__ inline float bs2f(short s) {
  union { short s; __hip_bfloat16 h; } u; u.s = s; return __bfloat162float(u.h);
}
// packed f32x4 -> bf16x4 (v_cvt_pk_bf16_f32 x2)
static __device__ inline short4v pk4(float a, float b, float c, float d) {
  union { __hip_bfloat162 h[2]; short4v s; } u;
  u.h[0] = __float22bfloat162_rn(float2{a, b});
  u.h[1] = __float22bfloat162_rn(float2{c, d});
  return u.s;
}

static __device__ inline float4v mfma32(short8 a, short8 b, float4v c) {
  return __builtin_amdgcn_mfma_f32_16x16x32_bf16(a, b, c, 0, 0, 0);
}
// v_mfma_f32_16x16x16_bf16 — "_1k" builtin, present on gfx950.
static __device__ inline float4v mfma16(short4v a, short4v b, float4v c) {
  return __builtin_amdgcn_mfma_f32_16x16x16bf16_1k(a, b, c, 0, 0, 0);
}

// ------- Stage A (fused): z<2 -> W transpose fp32->bf16; z==2 -> hs cvt -------
__global__ __launch_bounds__(256) void pre(
    const float* __restrict__ Wq, const float* __restrict__ Wk,
    const float* __restrict__ hs,
    __hip_bfloat16* __restrict__ Wqt, __hip_bfloat16* __restrict__ Wkt,
    __hip_bfloat16* __restrict__ hsb) {
  if (blockIdx.z == 2) {
    const int blk = blockIdx.y * 16 + blockIdx.x;
    for (int it = 0; it < 8; ++it) {
      const size_t i = (size_t)blk * 16384 + it * 2048 + threadIdx.x * 8;
      const float4v v0 = *(const float4v*)(hs + i);
      const float4v v1 = *(const float4v*)(hs + i + 4);
      short8 s;
      for (int j = 0; j < 4; ++j) { s[j] = f2bs(v0[j]); s[4 + j] = f2bs(v1[j]); }
      *(short8*)(hsb + i) = s;
    }
    return;
  }
  const float* W = blockIdx.z ? Wk : Wq;
  __hip_bfloat16* Wt = blockIdx.z ? Wkt : Wqt;
  __shared__ float t[64][65];
  const int n0 = blockIdx.x * 64, k0 = blockIdx.y * 64;
  const int c = threadIdx.x & 63, r0 = threadIdx.x >> 6;
  for (int i = 0; i < 16; ++i) {
    const int r = i * 4 + r0;
    t[c][r] = W[(size_t)(k0 + r) * D_ + n0 + c];
  }
  __syncthreads();
  for (int i = 0; i < 16; ++i) {
    const int rr = i * 4 + r0;
    Wt[(size_t)(n0 + rr) * D_ + k0 + c] = __float2bfloat16(t[rr][c]);
  }
}

// ---- Stage B (fused GEMM+prep): q-tile + k-tile of same 64x128 range; epilogue
// emits q, kt=softplus(k), and vT[b,h,d,s'] = q+k with s' KEY-SWIZZLED per
// 64-chunk (pos = ((s>>2)&3)*16 + ((s>>4)&3)*4 + (s&3)) so attn's PV
// A-fragments are contiguous 16B global loads.
__global__ __launch_bounds__(256) void gemm_fused(
    const __hip_bfloat16* __restrict__ A,
    const __hip_bfloat16* __restrict__ Wqt, const __hip_bfloat16* __restrict__ Wkt,
    const float* __restrict__ bq, const float* __restrict__ bk,
    __hip_bfloat16* __restrict__ q_out, __hip_bfloat16* __restrict__ kt_out,
    __hip_bfloat16* __restrict__ vT) {
  const int n0 = blockIdx.x * 128, m0 = blockIdx.y * 64;
  __shared__ __hip_bfloat16 As[2][64 * 32];
  __shared__ __hip_bfloat16 Bq[2][128 * 32];
  __shared__ __hip_bfloat16 Bk[2][128 * 32];
  const int tid = threadIdx.x, wid = tid >> 6, lane = tid & 63;
  const int wm = (wid >> 1) * 32, wn = (wid & 1) * 64;
  const int l15 = lane & 15, l4 = lane >> 4;
  const float4v zz = {0.f, 0.f, 0.f, 0.f};
  float4v accq[2][4], acck[2][4];
  for (int i = 0; i < 2; ++i)
    for (int j = 0; j < 4; ++j) { accq[i][j] = zz; acck[i][j] = zz; }
  const int arow = wid * 16 + (lane >> 2);
  const int brow = wid * 32 + (lane >> 2);
  const int lk8 = (lane & 3) * 8;
  gl_lds16(A + (size_t)(m0 + arow) * D_ + lk8, As[0] + wid * 512);
  gl_lds16(Wqt + (size_t)(n0 + brow) * D_ + lk8, Bq[0] + wid * 1024);
  gl_lds16(Wqt + (size_t)(n0 + brow + 16) * D_ + lk8, Bq[0] + wid * 1024 + 512);
  gl_lds16(Wkt + (size_t)(n0 + brow) * D_ + lk8, Bk[0] + wid * 1024);
  gl_lds16(Wkt + (size_t)(n0 + brow + 16) * D_ + lk8, Bk[0] + wid * 1024 + 512);
  int p = 0;
  for (int kb = 0; kb < 32; ++kb) {
    __syncthreads();
    if (kb < 31) {
      const int kc = (kb + 1) * 32 + lk8;
      gl_lds16(A + (size_t)(m0 + arow) * D_ + kc, As[p ^ 1] + wid * 512);
      gl_lds16(Wqt + (size_t)(n0 + brow) * D_ + kc, Bq[p ^ 1] + wid * 1024);
      gl_lds16(Wqt + (size_t)(n0 + brow + 16) * D_ + kc, Bq[p ^ 1] + wid * 1024 + 512);
      gl_lds16(Wkt + (size_t)(n0 + brow) * D_ + kc, Bk[p ^ 1] + wid * 1024);
      gl_lds16(Wkt + (size_t)(n0 + brow + 16) * D_ + kc, Bk[p ^ 1] + wid * 1024 + 512);
    }
    short8 af[2], bfq[4], bfk[4];
    const int fo = l4 * 8;
    for (int rt = 0; rt < 2; ++rt)
      af[rt] = *(const short8*)(As[p] + (wm + rt * 16 + l15) * 32 + fo);
    for (int ct = 0; ct < 4; ++ct) {
      bfq[ct] = *(const short8*)(Bq[p] + (wn + ct * 16 + l15) * 32 + fo);
      bfk[ct] = *(const short8*)(Bk[p] + (wn + ct * 16 + l15) * 32 + fo);
    }
    for (int rt = 0; rt < 2; ++rt)
      for (int ct = 0; ct < 4; ++ct) {
        accq[rt][ct] = mfma32(af[rt], bfq[ct], accq[rt][ct]);
        acck[rt][ct] = mfma32(af[rt], bfk[ct], acck[rt][ct]);
      }
    p ^= 1;
  }
  float bvq[4], bvk[4];
  for (int ct = 0; ct < 4; ++ct) {
    bvq[ct] = bq[n0 + wn + ct * 16 + l15];
    bvk[ct] = bk[n0 + wn + ct * 16 + l15];
  }
  for (int rt = 0; rt < 2; ++rt)
    for (int ct = 0; ct < 4; ++ct) {
      const int col = n0 + wn + ct * 16 + l15;
      const int h = col >> 6, d = col & 63;
      const int rowb = m0 + wm + rt * 16 + l4 * 4;
      short4v vv;
      for (int r = 0; r < 4; ++r) {
        const int row = rowb + r;
        const float qv = accq[rt][ct][r] + bvq[ct];
        const float kv = acck[rt][ct][r] + bvk[ct];
        const float sp = fmaxf(kv, 0.f) + __logf(1.f + __expf(-fabsf(kv)));
        q_out[(size_t)row * D_ + col] = __float2bfloat16(qv);
        kt_out[(size_t)row * D_ + col] = __float2bfloat16(sp);
        vv[r] = f2bs(qv + kv);
      }
      const int b = rowb >> 11, s = rowb & 2047;
      // key-swizzle within the 64-chunk (i=0 since s%4==0)
      const int sw = (s & ~63) | (((s >> 2) & 3) << 4) | (((s >> 4) & 3) << 2);
      *(short4v*)(vT + ((size_t)(b * H_ + h) * HD_ + d) * S_ + sw) = vv;
    }
}

// ------- Stage D: flash attention; kt in LDS (dbuf), V direct from L2 -------
// 512 thr = 8 waves; hf = key half, qt = 32-query stripe (tiles A/B).
// exp2-domain scores (0.125*log2e folded into q-frags; mask->0 exact).
// P (QK C-layout) feeds PV 16x16x16 MFMA directly; V fragments are 16B global
// loads thanks to the producer-side key swizzle.
#define KP 72  // row pad: 144 B, 16B-aligned rows
__global__ __launch_bounds__(512, 6) void attn(
    const __hip_bfloat16* __restrict__ qb, const __hip_bfloat16* __restrict__ ktb,
    const __hip_bfloat16* __restrict__ vT, const int* __restrict__ mask,
    float* __restrict__ out) {
  __shared__ __hip_bfloat16 smem[2][2 * 64 * KP];  // [buf][ kts[2][64][KP] ]
  const int q0 = blockIdx.x * 128, h = blockIdx.y, b = blockIdx.z;
  const int tid = threadIdx.x, wid = tid >> 6, lane = tid & 63;
  const int l15 = lane & 15, l4 = lane >> 4;
  const int hf = wid >> 2, qt = wid & 3;
  const __hip_bfloat16* qh = qb + (size_t)b * S_ * D_ + h * HD_;
  const __hip_bfloat16* kh = ktb + (size_t)b * S_ * D_ + h * HD_;
  const __hip_bfloat16* vh = vT + (size_t)(b * H_ + h) * HD_ * S_;
  const int srow = (tid & 255) >> 2;
  const int scol = (tid & 3) * 8;
  const int koff = hf * 64 * KP;

  const int qlA = qt * 32 + l15, qlB = qlA + 16;
  const int qrA = q0 + qlA, qrB = q0 + qlB;
  const float SC = 0.125f * 1.44269504f;  // /sqrt(64) * log2(e): exp2 domain
  const float mqA = (mask[b * S_ + qrA] != 0) ? SC : 0.f;
  const float mqB = (mask[b * S_ + qrB] != 0) ? SC : 0.f;
  const short8 rA0 = *(const short8*)(qh + (size_t)qrA * D_ + l4 * 8);
  const short8 rA1 = *(const short8*)(qh + (size_t)qrA * D_ + 32 + l4 * 8);
  const short8 rB0 = *(const short8*)(qh + (size_t)qrB * D_ + l4 * 8);
  const short8 rB1 = *(const short8*)(qh + (size_t)qrB * D_ + 32 + l4 * 8);
  short8 bqA0, bqA1, bqB0, bqB1;
  for (int j = 0; j < 8; ++j) {
    bqA0[j] = f2bs(bs2f(rA0[j]) * mqA);
    bqA1[j] = f2bs(bs2f(rA1[j]) * mqA);
    bqB0[j] = f2bs(bs2f(rB0[j]) * mqB);
    bqB1[j] = f2bs(bs2f(rB1[j]) * mqB);
  }

  const float4v zz = {0.f, 0.f, 0.f, 0.f};
  float4v oaccA[4] = {zz, zz, zz, zz};
  float4v oaccB[4] = {zz, zz, zz, zz};
  float lsumA = 0.f, lsumB = 0.f;

  const int kb0 = hf * 1024;
  short8 gk0 = *(const short8*)(kh + (size_t)(kb0 + srow) * D_ + scol);
  short8 gk1 = *(const short8*)(kh + (size_t)(kb0 + srow) * D_ + scol + 32);

  int p = 0;
  for (int c = 0; c < 16; ++c) {
    *(short8*)&smem[p][koff + srow * KP + scol] = gk0;
    *(short8*)&smem[p][koff + srow * KP + scol + 32] = gk1;
    __syncthreads();
    if (c < 15) {
      const int kb = hf * 1024 + (c + 1) * 64;
      gk0 = *(const short8*)(kh + (size_t)(kb + srow) * D_ + scol);
      gk1 = *(const short8*)(kh + (size_t)(kb + srow) * D_ + scol + 32);
    }
    const __hip_bfloat16* kb_ = &smem[p][koff];
    const __hip_bfloat16* vrow0 = vh + kb0 + c * 64;  // + d*S_ later
    // ---- phase 1: QK for all 4 key-tiles -> P fragments (exp2 domain) ----
    short4v pA[4], pB[4];
#pragma unroll
    for (int t = 0; t < 4; ++t) {
      const short8 ak0 = *(const short8*)&kb_[(t * 16 + l15) * KP + l4 * 8];
      const short8 ak1 = *(const short8*)&kb_[(t * 16 + l15) * KP + 32 + l4 * 8];
      float4v cA = zz, cB = zz;
      cA = mfma32(ak0, bqA0, cA);
      cA = mfma32(ak1, bqA1, cA);
      cB = mfma32(ak0, bqB0, cB);
      cB = mfma32(ak1, bqB1, cB);
      float eA[4], eB[4];
#pragma unroll
      for (int r = 0; r < 4; ++r) {
        eA[r] = __builtin_amdgcn_exp2f(cA[r]); lsumA += eA[r];
        eB[r] = __builtin_amdgcn_exp2f(cB[r]); lsumB += eB[r];
      }
      pA[t] = pk4(eA[0], eA[1], eA[2], eA[3]);
      pB[t] = pk4(eB[0], eB[1], eB[2], eB[3]);
    }
    // ---- phase 2: PV; V fragments direct from global (swizzled layout) ----
#pragma unroll
    for (int dt = 0; dt < 4; ++dt) {
      const __hip_bfloat16* vr = vrow0 + (size_t)(dt * 16 + l15) * S_ + l4 * 16;
      const short8 av0 = *(const short8*)vr;        // tiles 0,1 for this l4
      const short8 av1 = *(const short8*)(vr + 8);  // tiles 2,3
      const short4v a0 = {av0[0], av0[1], av0[2], av0[3]};
      const short4v a1 = {av0[4], av0[5], av0[6], av0[7]};
      const short4v a2 = {av1[0], av1[1], av1[2], av1[3]};
      const short4v a3 = {av1[4], av1[5], av1[6], av1[7]};
      oaccA[dt] = mfma16(a0, pA[0], oaccA[dt]);
      oaccB[dt] = mfma16(a0, pB[0], oaccB[dt]);
      oaccA[dt] = mfma16(a1, pA[1], oaccA[dt]);
      oaccB[dt] = mfma16(a1, pB[1], oaccB[dt]);
      oaccA[dt] = mfma16(a2, pA[2], oaccA[dt]);
      oaccB[dt] = mfma16(a2, pB[2], oaccB[dt]);
      oaccA[dt] = mfma16(a3, pA[3], oaccA[dt]);
      oaccB[dt] = mfma16(a3, pB[3], oaccB[dt]);
    }
    p ^= 1;
  }
  float lA = lsumA + __shfl_xor(lsumA, 16); lA += __shfl_xor(lA, 32);
  float lB = lsumB + __shfl_xor(lsumB, 16); lB += __shfl_xor(lB, 32);
  __syncthreads();
  float* mbuf = (float*)&smem[0][0];            // [128][68] = 34816 B (fits 36864)
  float* mlb = (float*)&smem[0][0] + 128 * 68;  // [128]
  if (hf == 1) {
#pragma unroll
    for (int dt = 0; dt < 4; ++dt)
#pragma unroll
      for (int r = 0; r < 4; ++r) {
        mbuf[qlA * 68 + dt * 16 + l4 * 4 + r] = oaccA[dt][r];
        mbuf[qlB * 68 + dt * 16 + l4 * 4 + r] = oaccB[dt][r];
      }
    if (l4 == 0) { mlb[qlA] = lA; mlb[qlB] = lB; }
  }
  __syncthreads();
  if (hf == 0) {
    const float liA = 1.f / (lA + mlb[qlA]);
    const float liB = 1.f / (lB + mlb[qlB]);
#pragma unroll
    for (int dt = 0; dt < 4; ++dt) {
      const float4v pa = *(const float4v*)&mbuf[qlA * 68 + dt * 16 + l4 * 4];
      const float4v pb = *(const float4v*)&mbuf[qlB * 68 + dt * 16 + l4 * 4];
      float4v va, vb;
#pragma unroll
      for (int r = 0; r < 4; ++r) {
        va[r] = (oaccA[dt][r] + pa[r]) * liA;
        vb[r] = (oaccB[dt][r] + pb[r]) * liB;
      }
      *(float4v*)(out + (size_t)(b * S_ + qrA) * D_ + h * HD_ + dt * 16 + l4 * 4) = va;
      *(float4v*)(out + (size_t)(b * S_ + qrB) * D_ + h * HD_ + dt * 16 + l4 * 4) = vb;
    }
  }
}

extern "C" void kernel_launch(void* const* d_in, const int* in_sizes, int n_in,
                              void* d_out, int out_size, void* d_ws, size_t ws_size,
                              hipStream_t stream) {
  const float* hs = (const float*)d_in[0];
  const int* mask = (const int*)d_in[1];
  const float* Wq = (const float*)d_in[2];
  const float* bq = (const float*)d_in[3];
  const float* Wk = (const float*)d_in[4];
  const float* bk = (const float*)d_in[5];
  float* out = (float*)d_out;
  char* ws = (char*)d_ws;
  const size_t MB = 1u << 20;
  __hip_bfloat16* q_b = (__hip_bfloat16*)(ws + 0 * MB);   // [B,S,D] bf16, 8MB
  __hip_bfloat16* k_b = (__hip_bfloat16*)(ws + 8 * MB);   // softplus(k), 8MB
  __hip_bfloat16* hsb = (__hip_bfloat16*)(ws + 16 * MB);  // hs bf16, 8MB
  __hip_bfloat16* vT  = (__hip_bfloat16*)(ws + 24 * MB);  // [B,H,HD,S] swizzled, 8MB
  __hip_bfloat16* Wqt = (__hip_bfloat16*)(ws + 32 * MB);  // 2MB
  __hip_bfloat16* Wkt = (__hip_bfloat16*)(ws + 34 * MB);  // 2MB

  pre<<<dim3(16, 16, 3), 256, 0, stream>>>(Wq, Wk, hs, Wqt, Wkt, hsb);
  gemm_fused<<<dim3(8, 64), 256, 0, stream>>>(hsb, Wqt, Wkt, bq, bk, q_b, k_b, vT);
  attn<<<dim3(16, 16, 2), 512, 0, stream>>>(q_b, k_b, vT, mask, out);
}

// Round 12
// 175.993 us; speedup vs baseline: 2.2045x; 2.2045x over previous
//
#include <hip/hip_runtime.h>
#include <hip/hip_bf16.h>

#define B_ 2
#define S_ 2048
#define D_ 1024
#define H_ 16
#define HD_ 64

typedef __attribute__((ext_vector_type(8))) short short8;
typedef __attribute__((ext_vector_type(4))) short short4v;
typedef __attribute__((ext_vector_type(4))) float float4v;

typedef const __attribute__((address_space(1))) void* gas_ptr;
typedef __attribute__((address_space(3))) void* las_ptr;

static __device__ inline void gl_lds16(const void* g, void* l) {
  __builtin_amdgcn_global_load_lds((gas_ptr)g, (las_ptr)l, 16, 0, 0);
}

static __device__ inline float b2f(__hip_bfloat16 h) { return __bfloat162float(h); }

static __device__ inline short f2bs(float x) {
  __hip_bfloat16 h = __float2bfloat16(x);
  union { __hip_bfloat16 h; short s; } u; u.h = h; return u.s;
}
static __device__ inline float bs2f(short s) {
  union { short s; __hip_bfloat16 h; } u; u.s = s; return __bfloat162float(u.h);
}
// packed f32x4 -> bf16x4 (v_cvt_pk_bf16_f32 x2)
static __device__ inline short4v pk4(float a, float b, float c, float d) {
  union { __hip_bfloat162 h[2]; short4v s; } u;
  u.h[0] = __float22bfloat162_rn(float2{a, b});
  u.h[1] = __float22bfloat162_rn(float2{c, d});
  return u.s;
}

static __device__ inline float4v mfma32(short8 a, short8 b, float4v c) {
  return __builtin_amdgcn_mfma_f32_16x16x32_bf16(a, b, c, 0, 0, 0);
}
// v_mfma_f32_16x16x16_bf16 — "_1k" builtin, present on gfx950.
static __device__ inline float4v mfma16(short4v a, short4v b, float4v c) {
  return __builtin_amdgcn_mfma_f32_16x16x16bf16_1k(a, b, c, 0, 0, 0);
}

// ------- Stage A (fused): z<2 -> W transpose fp32->bf16; z==2 -> hs cvt -------
__global__ __launch_bounds__(256) void pre(
    const float* __restrict__ Wq, const float* __restrict__ Wk,
    const float* __restrict__ hs,
    __hip_bfloat16* __restrict__ Wqt, __hip_bfloat16* __restrict__ Wkt,
    __hip_bfloat16* __restrict__ hsb) {
  if (blockIdx.z == 2) {
    const int blk = blockIdx.y * 16 + blockIdx.x;
    for (int it = 0; it < 8; ++it) {
      const size_t i = (size_t)blk * 16384 + it * 2048 + threadIdx.x * 8;
      const float4v v0 = *(const float4v*)(hs + i);
      const float4v v1 = *(const float4v*)(hs + i + 4);
      short8 s;
      for (int j = 0; j < 4; ++j) { s[j] = f2bs(v0[j]); s[4 + j] = f2bs(v1[j]); }
      *(short8*)(hsb + i) = s;
    }
    return;
  }
  const float* W = blockIdx.z ? Wk : Wq;
  __hip_bfloat16* Wt = blockIdx.z ? Wkt : Wqt;
  __shared__ float t[64][65];
  const int n0 = blockIdx.x * 64, k0 = blockIdx.y * 64;
  const int c = threadIdx.x & 63, r0 = threadIdx.x >> 6;
  for (int i = 0; i < 16; ++i) {
    const int r = i * 4 + r0;
    t[c][r] = W[(size_t)(k0 + r) * D_ + n0 + c];
  }
  __syncthreads();
  for (int i = 0; i < 16; ++i) {
    const int rr = i * 4 + r0;
    Wt[(size_t)(n0 + rr) * D_ + k0 + c] = __float2bfloat16(t[rr][c]);
  }
}

// ---- Stage B (fused GEMM+prep): q-tile + k-tile of same 64x128 range; epilogue
// emits q, kt=softplus(k), vT[b,h,d,s] = q+k (plain layout — r11's swizzle reverted).
__global__ __launch_bounds__(256) void gemm_fused(
    const __hip_bfloat16* __restrict__ A,
    const __hip_bfloat16* __restrict__ Wqt, const __hip_bfloat16* __restrict__ Wkt,
    const float* __restrict__ bq, const float* __restrict__ bk,
    __hip_bfloat16* __restrict__ q_out, __hip_bfloat16* __restrict__ kt_out,
    __hip_bfloat16* __restrict__ vT) {
  const int n0 = blockIdx.x * 128, m0 = blockIdx.y * 64;
  __shared__ __hip_bfloat16 As[2][64 * 32];
  __shared__ __hip_bfloat16 Bq[2][128 * 32];
  __shared__ __hip_bfloat16 Bk[2][128 * 32];
  const int tid = threadIdx.x, wid = tid >> 6, lane = tid & 63;
  const int wm = (wid >> 1) * 32, wn = (wid & 1) * 64;
  const int l15 = lane & 15, l4 = lane >> 4;
  const float4v zz = {0.f, 0.f, 0.f, 0.f};
  float4v accq[2][4], acck[2][4];
  for (int i = 0; i < 2; ++i)
    for (int j = 0; j < 4; ++j) { accq[i][j] = zz; acck[i][j] = zz; }
  const int arow = wid * 16 + (lane >> 2);
  const int brow = wid * 32 + (lane >> 2);
  const int lk8 = (lane & 3) * 8;
  gl_lds16(A + (size_t)(m0 + arow) * D_ + lk8, As[0] + wid * 512);
  gl_lds16(Wqt + (size_t)(n0 + brow) * D_ + lk8, Bq[0] + wid * 1024);
  gl_lds16(Wqt + (size_t)(n0 + brow + 16) * D_ + lk8, Bq[0] + wid * 1024 + 512);
  gl_lds16(Wkt + (size_t)(n0 + brow) * D_ + lk8, Bk[0] + wid * 1024);
  gl_lds16(Wkt + (size_t)(n0 + brow + 16) * D_ + lk8, Bk[0] + wid * 1024 + 512);
  int p = 0;
  for (int kb = 0; kb < 32; ++kb) {
    __syncthreads();
    if (kb < 31) {
      const int kc = (kb + 1) * 32 + lk8;
      gl_lds16(A + (size_t)(m0 + arow) * D_ + kc, As[p ^ 1] + wid * 512);
      gl_lds16(Wqt + (size_t)(n0 + brow) * D_ + kc, Bq[p ^ 1] + wid * 1024);
      gl_lds16(Wqt + (size_t)(n0 + brow + 16) * D_ + kc, Bq[p ^ 1] + wid * 1024 + 512);
      gl_lds16(Wkt + (size_t)(n0 + brow) * D_ + kc, Bk[p ^ 1] + wid * 1024);
      gl_lds16(Wkt + (size_t)(n0 + brow + 16) * D_ + kc, Bk[p ^ 1] + wid * 1024 + 512);
    }
    short8 af[2], bfq[4], bfk[4];
    const int fo = l4 * 8;
    for (int rt = 0; rt < 2; ++rt)
      af[rt] = *(const short8*)(As[p] + (wm + rt * 16 + l15) * 32 + fo);
    for (int ct = 0; ct < 4; ++ct) {
      bfq[ct] = *(const short8*)(Bq[p] + (wn + ct * 16 + l15) * 32 + fo);
      bfk[ct] = *(const short8*)(Bk[p] + (wn + ct * 16 + l15) * 32 + fo);
    }
    for (int rt = 0; rt < 2; ++rt)
      for (int ct = 0; ct < 4; ++ct) {
        accq[rt][ct] = mfma32(af[rt], bfq[ct], accq[rt][ct]);
        acck[rt][ct] = mfma32(af[rt], bfk[ct], acck[rt][ct]);
      }
    p ^= 1;
  }
  float bvq[4], bvk[4];
  for (int ct = 0; ct < 4; ++ct) {
    bvq[ct] = bq[n0 + wn + ct * 16 + l15];
    bvk[ct] = bk[n0 + wn + ct * 16 + l15];
  }
  for (int rt = 0; rt < 2; ++rt)
    for (int ct = 0; ct < 4; ++ct) {
      const int col = n0 + wn + ct * 16 + l15;
      const int h = col >> 6, d = col & 63;
      const int rowb = m0 + wm + rt * 16 + l4 * 4;
      short4v vv;
      for (int r = 0; r < 4; ++r) {
        const int row = rowb + r;
        const float qv = accq[rt][ct][r] + bvq[ct];
        const float kv = acck[rt][ct][r] + bvk[ct];
        const float sp = fmaxf(kv, 0.f) + __logf(1.f + __expf(-fabsf(kv)));
        q_out[(size_t)row * D_ + col] = __float2bfloat16(qv);
        kt_out[(size_t)row * D_ + col] = __float2bfloat16(sp);
        vv[r] = f2bs(qv + kv);
      }
      const int b = rowb >> 11, s = rowb & 2047;
      *(short4v*)(vT + ((size_t)(b * H_ + h) * HD_ + d) * S_ + s) = vv;
    }
}

// ------- Stage D: flash attention — 8 waves share one staged chunk -------
// 512 thr = 8 waves; wave wid owns queries [q0+wid*16, +16); full 2048-key
// loop, 32 chunks of 64 keys. kt+v staged in LDS (dbuf, 36.9 KB -> 4 blk/CU).
// exp2-domain scores (0.125*log2e folded into q-frags; mask->0 exact).
// QK C-layout P feeds PV 16x16x16 MFMA directly. Epilogue: LDS transpose for
// coalesced float4 stores (no key-split merge needed).
#define KP 72  // row pad: 144 B, 16B-aligned rows
__global__ __launch_bounds__(512, 8) void attn(
    const __hip_bfloat16* __restrict__ qb, const __hip_bfloat16* __restrict__ ktb,
    const __hip_bfloat16* __restrict__ vT, const int* __restrict__ mask,
    float* __restrict__ out) {
  __shared__ __hip_bfloat16 smem[2][2 * 64 * KP];  // [buf][ kts[64][KP] ++ vts[64][KP] ]
  const int q0 = blockIdx.x * 128, h = blockIdx.y, b = blockIdx.z;
  const int tid = threadIdx.x, wid = tid >> 6, lane = tid & 63;
  const int l15 = lane & 15, l4 = lane >> 4;
  const __hip_bfloat16* qh = qb + (size_t)b * S_ * D_ + h * HD_;
  const __hip_bfloat16* kh = ktb + (size_t)b * S_ * D_ + h * HD_;
  const __hip_bfloat16* vh = vT + (size_t)(b * H_ + h) * HD_ * S_;
  const int voff = 64 * KP;  // vts base within buffer
  // staging map: all 512 threads, one short8 per tensor. row=tid>>3, col=(tid&7)*8
  const int srow = tid >> 3;
  const int scol = (tid & 7) * 8;

  // q B-fragment (n = query = l15); mask*scale*log2e folded in
  const int ql = wid * 16 + l15;       // query-local
  const int qr = q0 + ql;              // global query row
  const float SC = 0.125f * 1.44269504f;
  const float mq = (mask[b * S_ + qr] != 0) ? SC : 0.f;
  const short8 rq0 = *(const short8*)(qh + (size_t)qr * D_ + l4 * 8);
  const short8 rq1 = *(const short8*)(qh + (size_t)qr * D_ + 32 + l4 * 8);
  short8 bq0, bq1;
  for (int j = 0; j < 8; ++j) {
    bq0[j] = f2bs(bs2f(rq0[j]) * mq);
    bq1[j] = f2bs(bs2f(rq1[j]) * mq);
  }

  const float4v zz = {0.f, 0.f, 0.f, 0.f};
  float4v oacc[4] = {zz, zz, zz, zz};
  float lsum = 0.f;

  // prefetch chunk 0
  short8 gk = *(const short8*)(kh + (size_t)srow * D_ + scol);          // kt[key][dim]
  short8 gv = *(const short8*)(vh + (size_t)srow * S_ + scol);          // v[dim][key]

  int p = 0;
  for (int c = 0; c < 32; ++c) {
    *(short8*)&smem[p][srow * KP + scol] = gk;
    *(short8*)&smem[p][voff + srow * KP + scol] = gv;
    __syncthreads();  // buf[p] visible; all waves' reads of buf[p] (from c-2) done
    if (c < 31) {
      const int kb = (c + 1) * 64;
      gk = *(const short8*)(kh + (size_t)(kb + srow) * D_ + scol);
      gv = *(const short8*)(vh + (size_t)srow * S_ + kb + scol);
    }
    const __hip_bfloat16* kb_ = &smem[p][0];
    const __hip_bfloat16* vb_ = &smem[p][voff];
#pragma unroll
    for (int t = 0; t < 4; ++t) {  // 16-key tile
      const short8 ak0 = *(const short8*)&kb_[(t * 16 + l15) * KP + l4 * 8];
      const short8 ak1 = *(const short8*)&kb_[(t * 16 + l15) * KP + 32 + l4 * 8];
      float4v cc = zz;
      cc = mfma32(ak0, bq0, cc);
      cc = mfma32(ak1, bq1, cc);
      float e[4];
#pragma unroll
      for (int r = 0; r < 4; ++r) { e[r] = __builtin_amdgcn_exp2f(cc[r]); lsum += e[r]; }
      const short4v pf = pk4(e[0], e[1], e[2], e[3]);
#pragma unroll
      for (int dt = 0; dt < 4; ++dt) {
        const short4v av = *(const short4v*)&vb_[(dt * 16 + l15) * KP + t * 16 + l4 * 4];
        oacc[dt] = mfma16(av, pf, oacc[dt]);
      }
    }
    p ^= 1;
  }
  // ---- epilogue: quad-reduce l; LDS transpose for coalesced stores ----
  float l = lsum + __shfl_xor(lsum, 16); l += __shfl_xor(l, 32);
  __syncthreads();  // all frag reads done -> overlay buffers on smem
  float* mbuf = (float*)&smem[0][0];            // [128][68] = 34816 B
  float* mlb = (float*)&smem[0][0] + 128 * 68;  // [128] (total 35328 <= 36864)
  #pragma unroll
  for (int dt = 0; dt < 4; ++dt)
#pragma unroll
    for (int r = 0; r < 4; ++r)
      mbuf[ql * 68 + dt * 16 + l4 * 4 + r] = oacc[dt][r];
  if (l4 == 0) mlb[ql] = l;
  __syncthreads();
  const int qq = wid * 16 + (lane >> 2);   // this lane stores query qq's dims
  const int dg = (lane & 3) * 16;
  const float li = 1.f / mlb[qq];
  float* orow = out + (size_t)(b * S_ + q0 + qq) * D_ + h * HD_ + dg;
#pragma unroll
  for (int i = 0; i < 4; ++i) {
    float4v v = *(const float4v*)&mbuf[qq * 68 + dg + i * 4];
#pragma unroll
    for (int r = 0; r < 4; ++r) v[r] *= li;
    *(float4v*)(orow + i * 4) = v;
  }
}

extern "C" void kernel_launch(void* const* d_in, const int* in_sizes, int n_in,
                              void* d_out, int out_size, void* d_ws, size_t ws_size,
                              hipStream_t stream) {
  const float* hs = (const float*)d_in[0];
  const int* mask = (const int*)d_in[1];
  const float* Wq = (const float*)d_in[2];
  const float* bq = (const float*)d_in[3];
  const float* Wk = (const float*)d_in[4];
  const float* bk = (const float*)d_in[5];
  float* out = (float*)d_out;
  char* ws = (char*)d_ws;
  const size_t MB = 1u << 20;
  __hip_bfloat16* q_b = (__hip_bfloat16*)(ws + 0 * MB);   // [B,S,D] bf16, 8MB
  __hip_bfloat16* k_b = (__hip_bfloat16*)(ws + 8 * MB);   // softplus(k), 8MB
  __hip_bfloat16* hsb = (__hip_bfloat16*)(ws + 16 * MB);  // hs bf16, 8MB
  __hip_bfloat16* vT  = (__hip_bfloat16*)(ws + 24 * MB);  // [B,H,HD,S] 8MB
  __hip_bfloat16* Wqt = (__hip_bfloat16*)(ws + 32 * MB);  // 2MB
  __hip_bfloat16* Wkt = (__hip_bfloat16*)(ws + 34 * MB);  // 2MB

  pre<<<dim3(16, 16, 3), 256, 0, stream>>>(Wq, Wk, hs, Wqt, Wkt, hsb);
  gemm_fused<<<dim3(8, 64), 256, 0, stream>>>(hsb, Wqt, Wkt, bq, bk, q_b, k_b, vT);
  attn<<<dim3(16, 16, 2), 512, 0, stream>>>(q_b, k_b, vT, mask, out);
}